// Round 15
// baseline (110.310 us; speedup 1.0000x reference)
//
#include <hip/hip_runtime.h>

#define NN 160      // nodes
#define BB 128      // batch
#define HH 256      // hidden
#define EE 5120     // edges
#define ST 128      // state dim
#define AC 32       // action dim

typedef __attribute__((ext_vector_type(8))) short short8;
typedef __attribute__((ext_vector_type(4))) short bf16x4;
typedef __attribute__((ext_vector_type(4))) float f32x4;
typedef unsigned short us;

__device__ inline us f2b(float f) {
    unsigned u = __builtin_bit_cast(unsigned, f);
    unsigned r = (u + 0x7FFFu + ((u >> 16) & 1u)) >> 16;
    return (us)r;
}
__device__ inline float b2f(us h) {
    return __builtin_bit_cast(float, (unsigned)h << 16);
}

// ---------- K1: graph rows + Pb/Mb (int-exact) + weight transposes + out init ----------
__global__ __launch_bounds__(256)
void k_pre(const int* __restrict__ ei, const float* __restrict__ W1,
           const float* __restrict__ W2, const float* __restrict__ state,
           const float* __restrict__ bo, us* __restrict__ Pb,
           us* __restrict__ Mb, us* __restrict__ W1t, us* __restrict__ W2t,
           float* __restrict__ out)
{
    const int bx = blockIdx.x, tid = threadIdx.x;
    if (bx < NN) {
        __shared__ int crow[NN];
        __shared__ unsigned abit[NN * NN / 32];   // 3.2 KB
        __shared__ float invdeg;
        if (tid < NN) crow[tid] = 0;
        for (int i = tid; i < NN * NN / 32; i += 256) abit[i] = 0;
        __syncthreads();
        for (int e = tid; e < EE; e += 256) {
            int s = ei[e], d = ei[EE + e];
            int p = d * NN + s;
            atomicOr(&abit[p >> 5], 1u << (p & 31));
            if (d == bx) atomicAdd(&crow[s], 1);
        }
        if (tid < NN) {
            int p = tid * NN + tid;
            atomicOr(&abit[p >> 5], 1u << (p & 31));
        }
        __syncthreads();
        if (tid == 0) {
            int dg = 0;
            for (int j = 0; j < NN; j++) dg += crow[j];
            invdeg = 1.0f / (float)(dg < 1 ? 1 : dg);
        }
        __syncthreads();
        if (tid < NN) {
            int s = 0;
            for (int k = 0; k < NN; k++) {
                int p = k * NN + tid;
                if (abit[p >> 5] & (1u << (p & 31))) s += crow[k];
            }
            Pb[bx * NN + tid] = f2b((float)s * invdeg);
            Mb[bx * NN + tid] = f2b((float)crow[tid] * invdeg);
        }
    } else if (bx < NN + 160) {                   // W1t: 256x160
        int idx = (bx - NN) * 256 + tid;
        int n = idx / NN, k = idx - n * NN;
        W1t[idx] = f2b(W1[k * HH + n]);
    } else if (bx < NN + 160 + 256) {             // W2t: 256x256
        int idx = (bx - NN - 160) * 256 + tid;
        int n = idx >> 8, k = idx & 255;
        W2t[idx] = f2b(W2[k * HH + n]);
    } else {                                      // out init: 128x128
        int idx = (bx - NN - 160 - 256) * 256 + tid;
        out[idx] = state[idx] + bo[idx & 127];
    }
}

// ---------- G1: h1t[b][h][i] = relu( sum_j W1t[h][j] * Pb[i][j]*x[b][j] + b1[h] )
// grid (2 h-half, 2 i-half, 128 b) = 512 blocks, 256 thr, ~17 KB LDS (2+/CU)
__global__ __launch_bounds__(256)
void k_g1(const us* __restrict__ Pb, const float* __restrict__ state,
          const float* __restrict__ action, const us* __restrict__ W1t,
          const float* __restrict__ b1, us* __restrict__ h1t)
{
    __shared__ __align__(16) us sA[128 * 40];   // W1t-half rows (h)
    __shared__ __align__(16) us sB[80 * 40];    // Y rows (i-half)
    __shared__ float xb[NN];
    const int ho = blockIdx.x * 128, ibase = blockIdx.y * 80, b = blockIdx.z;
    const int tid = threadIdx.x, lane = tid & 63, w = tid >> 6;
    const int rl = lane & 15, kq = lane >> 4;

    if (tid < NN) xb[tid] = (tid < ST) ? state[b * ST + tid]
                                       : action[b * AC + (tid - ST)];
    __syncthreads();

    f32x4 acc[2][5];
#pragma unroll
    for (int f = 0; f < 2; f++)
#pragma unroll
        for (int j = 0; j < 5; j++) acc[f][j] = f32x4{0.f, 0.f, 0.f, 0.f};

    for (int kk = 0; kk < 5; kk++) {
        const int k0 = kk * 32;
        for (int c = tid; c < 832; c += 256) {
            if (c < 512) {                       // A: W1t-half [128][32]
                int r = c >> 2, cc = (c & 3) * 8;
                *(short8*)&sA[r * 40 + cc] =
                    *(const short8*)&W1t[(size_t)(ho + r) * NN + k0 + cc];
            } else {                             // Bt: Y on the fly [80][32]
                int q = c - 512;
                int r = q >> 2, cc = (q & 3) * 8;
                short8 p = *(const short8*)&Pb[(size_t)(ibase + r) * NN + k0 + cc];
                short8 y;
#pragma unroll
                for (int u = 0; u < 8; u++)
                    y[u] = (short)f2b(b2f((us)p[u]) * xb[k0 + cc + u]);
                *(short8*)&sB[r * 40 + cc] = y;
            }
        }
        __syncthreads();
        short8 af[2], bf[5];
#pragma unroll
        for (int f = 0; f < 2; f++)
            af[f] = *(const short8*)&sA[(w * 32 + f * 16 + rl) * 40 + kq * 8];
#pragma unroll
        for (int j = 0; j < 5; j++)
            bf[j] = *(const short8*)&sB[(j * 16 + rl) * 40 + kq * 8];
#pragma unroll
        for (int f = 0; f < 2; f++)
#pragma unroll
            for (int j = 0; j < 5; j++)
                acc[f][j] = __builtin_amdgcn_mfma_f32_16x16x32_bf16(
                    af[f], bf[j], acc[f][j], 0, 0, 0);
        __syncthreads();
    }
    // epi: D[h][i]: row h = w*32+f*16+kq*4+r, col i = j*16+rl (coalesced over rl)
#pragma unroll
    for (int f = 0; f < 2; f++)
#pragma unroll
        for (int r = 0; r < 4; r++) {
            int h = ho + w * 32 + f * 16 + kq * 4 + r;
            float bias = b1[h];
#pragma unroll
            for (int j = 0; j < 5; j++) {
                int ig = ibase + j * 16 + rl;
                float v = acc[f][j][r] + bias;
                h1t[((size_t)b * HH + h) * NN + ig] = f2b(v > 0.f ? v : 0.f);
            }
        }
}

// ---------- G23: fused agg2 + mm2 + pool + head per (i-slice 32, b) ----------
// G2: ts[i'][h] = sum_k Mb[i0+i'][k]*h1t[b][h][k]   (barrier-free, resident)
// G3: acc3[i'][h'] = sum_h ts[i'][h]*W2t[h'][h]     (W2t dbuf, issue-early)
// pool over 32 i' rows -> head partial -> atomicAdd out
// grid (5, 128) = 640 blocks, 256 thr, 70.6 KB LDS => 2 blocks/CU
#define MBOFF 0        // [32][168]  = 5376 sh
#define H1OFF 5376     // [128][168] = 21504 sh
#define TSOFF 26880    // [32][264]  = 8448 sh  -> total 35328 sh = 70656 B
#define W2OFF 5376     // [2][256][40] = 20480 sh, overlays dead H1
__global__ __launch_bounds__(256)
void k_g23(const us* __restrict__ Mb, const us* __restrict__ h1t,
           const us* __restrict__ W2t, const float* __restrict__ b2,
           const float* __restrict__ Wo, float* __restrict__ out)
{
    __shared__ __align__(16) us SH[35328];
    const int iq = blockIdx.x, b = blockIdx.y, i0 = iq * 32;
    const int tid = threadIdx.x, lane = tid & 63, w = tid >> 6;  // 4 waves
    const int rl = lane & 15, kq = lane >> 4;

    // stage Mb slice: 32 rows x 20 chunks
    for (int c = tid; c < 640; c += 256) {
        int r = c / 20, col = (c % 20) * 8;
        *(short8*)&SH[MBOFF + r * 168 + col] =
            *(const short8*)&Mb[(size_t)(i0 + r) * NN + col];
    }

    // ---- G2 over hidden halves ----
    for (int hh = 0; hh < 2; hh++) {
        const int ho = hh * 128;
        for (int c = tid; c < 2560; c += 256) {   // stage h1t half [128][160]
            int r = c / 20, col = (c % 20) * 8;
            *(short8*)&SH[H1OFF + r * 168 + col] =
                *(const short8*)&h1t[((size_t)b * HH + ho + r) * NN + col];
        }
        __syncthreads();

        f32x4 acc2[2][2];
#pragma unroll
        for (int f = 0; f < 2; f++)
#pragma unroll
            for (int j = 0; j < 2; j++) acc2[f][j] = f32x4{0.f, 0.f, 0.f, 0.f};

        for (int kk = 0; kk < 5; kk++) {          // barrier-free
            const int k0 = kk * 32;
            short8 af[2], bf[2];
#pragma unroll
            for (int f = 0; f < 2; f++)
                af[f] = *(const short8*)&SH[H1OFF + (w * 32 + f * 16 + rl) * 168 + k0 + kq * 8];
#pragma unroll
            for (int j = 0; j < 2; j++)
                bf[j] = *(const short8*)&SH[MBOFF + (j * 16 + rl) * 168 + k0 + kq * 8];
#pragma unroll
            for (int f = 0; f < 2; f++)
#pragma unroll
                for (int j = 0; j < 2; j++)
                    acc2[f][j] = __builtin_amdgcn_mfma_f32_16x16x32_bf16(
                        af[f], bf[j], acc2[f][j], 0, 0, 0);
        }
        // epi: D[h][i']: 4 consec h per lane -> packed ts[i'][ho+h0..3]
#pragma unroll
        for (int f = 0; f < 2; f++) {
            int h0 = w * 32 + f * 16 + kq * 4;
#pragma unroll
            for (int j = 0; j < 2; j++) {
                int ip = j * 16 + rl;
                bf16x4 v;
#pragma unroll
                for (int r = 0; r < 4; r++)
                    v[r] = (short)f2b(acc2[f][j][r]);
                *(bf16x4*)&SH[TSOFF + ip * 264 + ho + h0] = v;
            }
        }
        __syncthreads();   // H1 reads done (next stage / W2 overlay safe)
    }

    // ---- G3: stage W2t step0 into buf0 (over dead H1) ----
#pragma unroll
    for (int c = 0; c < 4; c++)
        *(short8*)&SH[W2OFF + tid * 40 + c * 8] =
            *(const short8*)&W2t[(size_t)tid * HH + c * 8];
    __syncthreads();

    f32x4 acc3[2][4];
#pragma unroll
    for (int f = 0; f < 2; f++)
#pragma unroll
        for (int j = 0; j < 4; j++) acc3[f][j] = f32x4{0.f, 0.f, 0.f, 0.f};

    for (int kk = 0; kk < 8; kk++) {
        const int cur = (kk & 1) * 10240;
        short8 wn0, wn1, wn2, wn3;
        if (kk < 7) {   // T14 issue-early
            wn0 = *(const short8*)&W2t[(size_t)tid * HH + (kk + 1) * 32 + 0];
            wn1 = *(const short8*)&W2t[(size_t)tid * HH + (kk + 1) * 32 + 8];
            wn2 = *(const short8*)&W2t[(size_t)tid * HH + (kk + 1) * 32 + 16];
            wn3 = *(const short8*)&W2t[(size_t)tid * HH + (kk + 1) * 32 + 24];
        }
        short8 af[2], bf[4];
#pragma unroll
        for (int f = 0; f < 2; f++)
            af[f] = *(const short8*)&SH[TSOFF + (f * 16 + rl) * 264 + kk * 32 + kq * 8];
#pragma unroll
        for (int j = 0; j < 4; j++)
            bf[j] = *(const short8*)&SH[W2OFF + cur + (w * 64 + j * 16 + rl) * 40 + kq * 8];
#pragma unroll
        for (int f = 0; f < 2; f++)
#pragma unroll
            for (int j = 0; j < 4; j++)
                acc3[f][j] = __builtin_amdgcn_mfma_f32_16x16x32_bf16(
                    af[f], bf[j], acc3[f][j], 0, 0, 0);
        if (kk < 7) {   // write-late into idle buffer
            int o = W2OFF + (cur ^ 10240) + tid * 40;
            *(short8*)&SH[o + 0]  = wn0;
            *(short8*)&SH[o + 8]  = wn1;
            *(short8*)&SH[o + 16] = wn2;
            *(short8*)&SH[o + 24] = wn3;
        }
        __syncthreads();
    }

    // ---- pool over this block's 32 i' rows (8 per lane), slot by kq ----
    float* pp  = (float*)SH;          // [4][256] over dead Mb region
    float* phs = pp + 1024;           // [256]
    float* pts = pp + 1280;           // [2][128]
#pragma unroll
    for (int j = 0; j < 4; j++) {
        int hx = w * 64 + j * 16 + rl;
        float bias = b2[hx];
        float s = 0.f;
#pragma unroll
        for (int f = 0; f < 2; f++)
#pragma unroll
            for (int r = 0; r < 4; r++) {
                float v = acc3[f][j][r] + bias;
                s += v > 0.f ? v : 0.f;
            }
        pp[kq * 256 + hx] = s;
    }
    __syncthreads();
    phs[tid] = pp[tid] + pp[256 + tid] + pp[512 + tid] + pp[768 + tid];
    __syncthreads();
    // ---- head partial: out[b][s] += (sum_h phs[h]*Wo[h][s]) / NN ----
    {
        const int q = tid >> 7, s2 = tid & 127;
        float part = 0.f;
        for (int hx = q * 128; hx < q * 128 + 128; hx++)
            part += phs[hx] * Wo[(size_t)hx * ST + s2];
        pts[q * 128 + s2] = part;
        __syncthreads();
        if (tid < ST)
            atomicAdd(&out[b * ST + tid], (pts[tid] + pts[128 + tid]) * (1.0f / NN));
    }
}

extern "C" void kernel_launch(void* const* d_in, const int* in_sizes, int n_in,
                              void* d_out, int out_size, void* d_ws, size_t ws_size,
                              hipStream_t stream) {
    const float* state  = (const float*)d_in[0];
    const float* action = (const float*)d_in[1];
    const int*   ei     = (const int*)d_in[2];
    const float* W1     = (const float*)d_in[3];
    const float* b1     = (const float*)d_in[4];
    const float* W2     = (const float*)d_in[5];
    const float* b2     = (const float*)d_in[6];
    const float* Wo     = (const float*)d_in[7];
    const float* bo     = (const float*)d_in[8];
    float* out = (float*)d_out;

    char* ws = (char*)d_ws;
    size_t off = 0;
    auto alloc = [&](size_t bytes) {
        void* p = ws + off;
        off += (bytes + 255) & ~(size_t)255;
        return p;
    };
    us* Pb  = (us*)alloc(NN * NN * 2);
    us* Mb  = (us*)alloc(NN * NN * 2);
    us* W1t = (us*)alloc((size_t)HH * NN * 2);
    us* W2t = (us*)alloc((size_t)HH * HH * 2);
    us* h1t = (us*)alloc((size_t)BB * HH * NN * 2);   // [b][h][i]  10.5 MB

    k_pre<<<NN + 160 + 256 + 64, 256, 0, stream>>>(ei, W1, W2, state, bo,
                                                   Pb, Mb, W1t, W2t, out);
    {
        dim3 g1(2, 2, BB);   // 512 blocks
        k_g1<<<g1, 256, 0, stream>>>(Pb, state, action, W1t, b1, h1t);
    }
    {
        dim3 g23(5, BB);     // 640 blocks
        k_g23<<<g23, 256, 0, stream>>>(Mb, h1t, W2t, b2, Wo, out);
    }
}

// Round 16
// 38.393 us; speedup vs baseline: 2.8731x; 2.8731x over previous
//
#include <hip/hip_runtime.h>

#define NN 160      // nodes
#define BB 128      // batch
#define HH 256      // hidden
#define EE 5120     // edges
#define ST 128      // state dim
#define AC 32       // action dim
#define IH 80       // i-half rows

typedef __attribute__((ext_vector_type(8))) short short8;
typedef __attribute__((ext_vector_type(4))) short bf16x4;
typedef unsigned short us;
typedef __attribute__((ext_vector_type(4))) float f32x4;

__device__ inline us f2b(float f) {
    unsigned u = __builtin_bit_cast(unsigned, f);
    unsigned r = (u + 0x7FFFu + ((u >> 16) & 1u)) >> 16;
    return (us)r;
}
__device__ inline float b2f(us h) {
    return __builtin_bit_cast(float, (unsigned)h << 16);
}

// ---------- K1: graph rows + Pb/Mb (int-exact) + weight transposes + out init ----------
__global__ __launch_bounds__(256)
void k_pre(const int* __restrict__ ei, const float* __restrict__ W1,
           const float* __restrict__ W2, const float* __restrict__ state,
           const float* __restrict__ bo, us* __restrict__ Pb,
           us* __restrict__ Mb, us* __restrict__ W1t, us* __restrict__ W2t,
           float* __restrict__ out)
{
    const int bx = blockIdx.x, tid = threadIdx.x;
    if (bx < NN) {
        __shared__ int crow[NN];
        __shared__ unsigned abit[NN * NN / 32];   // 3.2 KB
        __shared__ float invdeg;
        if (tid < NN) crow[tid] = 0;
        for (int i = tid; i < NN * NN / 32; i += 256) abit[i] = 0;
        __syncthreads();
        for (int e = tid; e < EE; e += 256) {
            int s = ei[e], d = ei[EE + e];
            int p = d * NN + s;
            atomicOr(&abit[p >> 5], 1u << (p & 31));
            if (d == bx) atomicAdd(&crow[s], 1);
        }
        if (tid < NN) {
            int p = tid * NN + tid;
            atomicOr(&abit[p >> 5], 1u << (p & 31));
        }
        __syncthreads();
        if (tid == 0) {
            int dg = 0;
            for (int j = 0; j < NN; j++) dg += crow[j];
            invdeg = 1.0f / (float)(dg < 1 ? 1 : dg);
        }
        __syncthreads();
        if (tid < NN) {
            int s = 0;
            for (int k = 0; k < NN; k++) {
                int p = k * NN + tid;
                if (abit[p >> 5] & (1u << (p & 31))) s += crow[k];
            }
            Pb[bx * NN + tid] = f2b((float)s * invdeg);
            Mb[bx * NN + tid] = f2b((float)crow[tid] * invdeg);
        }
    } else if (bx < NN + 160) {                   // W1t: 256x160
        int idx = (bx - NN) * 256 + tid;
        int n = idx / NN, k = idx - n * NN;
        W1t[idx] = f2b(W1[k * HH + n]);
    } else if (bx < NN + 160 + 256) {             // W2t: 256x256
        int idx = (bx - NN - 160) * 256 + tid;
        int n = idx >> 8, k = idx & 255;
        W2t[idx] = f2b(W2[k * HH + n]);
    } else {                                      // out init: 128x128
        int idx = (bx - NN - 160 - 256) * 256 + tid;
        out[idx] = state[idx] + bo[idx & 127];
    }
}

// ---------- K2: 256 blocks = (i-half, batch), 1024 threads (16 waves) ----------
// G1 (full, dup x2): h1[h][k-node] = relu(sum_j Y[k][j]*W1t[h][j] + b1[h])
// G2 (i-half):       t[i'][h] = sum_k Mb[i0+i'][k]*h1[h][k]
// G3 (i-half):       acc = t @ W2t^T; relu+bias -> pool -> head -> atomic out
__global__ __launch_bounds__(1024, 4)
void k_mega(const us* __restrict__ Pb, const float* __restrict__ state,
            const float* __restrict__ action, const us* __restrict__ W1t,
            const float* __restrict__ b1, const us* __restrict__ Mb,
            const us* __restrict__ W2t, const float* __restrict__ b2,
            const float* __restrict__ Wo, float* __restrict__ out)
{
    __shared__ __align__(16) us h1s[256 * 168];   // 86016 B : h1 / W2t-dbuf
    __shared__ __align__(16) us R1[34560];        // 69120 B : {Y,W1t} -> {Mb,t,pp}
    __shared__ float xb[NN];
    us* Ys  = R1;                 // [160][40]  (12.8 KB)
    us* W1s = R1 + 6400;          // [128][168] (43 KB)
    us* Mbs = R1;                 // [80][168]  (26.9 KB)
    us* ts  = R1 + 13440;         // [80][264]  (42.2 KB)
    us* W2s = h1s;                // [2][256][40] dbuf (2x20.5 KB)
    float* pp  = (float*)R1;          // [4][256]  (4 KB, over dead Mbs)
    float* pts = (float*)(R1 + 2048); // [8][128]  (4 KB)

    const int ihalf = blockIdx.x, b = blockIdx.y, i_base = ihalf * IH;
    const int tid = threadIdx.x, lane = tid & 63, w = tid >> 6;  // 16 waves
    const int rl = lane & 15, kq = lane >> 4;
    const int wr = w >> 3, wc = w & 7;            // G1 tiling 2(i) x 8(h)
    const int rY = tid >> 2, cY = (tid & 3) * 8;  // Y chunk (tid<640)
    const int rD = tid >> 2, cD = (tid & 3) * 8;  // W2t chunk (1024 = 256x4)

    if (tid < NN) xb[tid] = (tid < ST) ? state[b * ST + tid]
                                       : action[b * AC + (tid - ST)];
    __syncthreads();

    // ======== G1 (duplicated): per hh half of hidden dim ========
    for (int hh = 0; hh < 2; hh++) {
        // stage W1t half (resident) + Y step0 (streamed)
        for (int c = tid; c < 2560; c += 1024) {
            int r = c / 20, col = (c - r * 20 / 1 * 20) * 8;
            col = (c % 20) * 8;
            *(short8*)&W1s[r * 168 + col] =
                *(const short8*)&W1t[(size_t)(hh * 128 + r) * NN + col];
        }
        if (tid < 640) {
            short8 p = *(const short8*)&Pb[rY * NN + cY];
            short8 y;
#pragma unroll
            for (int u = 0; u < 8; u++)
                y[u] = (short)f2b(b2f((us)p[u]) * xb[cY + u]);
            *(short8*)&Ys[rY * 40 + cY] = y;
        }
        __syncthreads();

        f32x4 acc1[5];
#pragma unroll
        for (int f = 0; f < 5; f++) acc1[f] = f32x4{0.f, 0.f, 0.f, 0.f};

        for (int k0 = 0; k0 < NN; k0 += 32) {
            const bool nxt = (k0 + 32) < NN;
            short8 p;
            if (nxt && tid < 640)   // T14: issue early
                p = *(const short8*)&Pb[rY * NN + k0 + 32 + cY];
            short8 af[5], bv;
#pragma unroll
            for (int f = 0; f < 5; f++)
                af[f] = *(const short8*)&Ys[(wr * 80 + f * 16 + rl) * 40 + kq * 8];
            bv = *(const short8*)&W1s[(wc * 16 + rl) * 168 + k0 + kq * 8];
#pragma unroll
            for (int f = 0; f < 5; f++)
                acc1[f] = __builtin_amdgcn_mfma_f32_16x16x32_bf16(
                    af[f], bv, acc1[f], 0, 0, 0);
            __syncthreads();
            if (nxt && tid < 640) {   // write-late
                short8 y;
#pragma unroll
                for (int u = 0; u < 8; u++)
                    y[u] = (short)f2b(b2f((us)p[u]) * xb[k0 + 32 + cY + u]);
                *(short8*)&Ys[rY * 40 + cY] = y;
            }
            __syncthreads();
        }
        // epi: D[i][h]: reg-quad = 4 consecutive i -> packed h1s[h][i0..3]
        {
            int h = hh * 128 + wc * 16 + rl;
            float bias = b1[h];
#pragma unroll
            for (int f = 0; f < 5; f++) {
                int i0 = wr * 80 + f * 16 + kq * 4;
                bf16x4 v;
#pragma unroll
                for (int r = 0; r < 4; r++) {
                    float t = acc1[f][r] + bias;
                    v[r] = (short)f2b(t > 0.f ? t : 0.f);
                }
                *(bf16x4*)&h1s[h * 168 + i0] = v;
            }
        }
    }
    __syncthreads();   // G1 done: R1 free for Mbs/ts; h1s complete

    // ======== G2: D[h 256][i' 80], K=160(k). wave w -> h rows [16w,16w+16) ========
    {
        for (int c = tid; c < 1600; c += 1024) {
            int r = c / 20, col = (c % 20) * 8;
            *(short8*)&Mbs[r * 168 + col] =
                *(const short8*)&Mb[(size_t)(i_base + r) * NN + col];
        }
        __syncthreads();

        f32x4 acc2[5];
#pragma unroll
        for (int j = 0; j < 5; j++) acc2[j] = f32x4{0.f, 0.f, 0.f, 0.f};

        for (int k0 = 0; k0 < NN; k0 += 32) {    // barrier-free (both resident)
            short8 a = *(const short8*)&h1s[(w * 16 + rl) * 168 + k0 + kq * 8];
            short8 bfv[5];
#pragma unroll
            for (int j = 0; j < 5; j++)
                bfv[j] = *(const short8*)&Mbs[(j * 16 + rl) * 168 + k0 + kq * 8];
#pragma unroll
            for (int j = 0; j < 5; j++)
                acc2[j] = __builtin_amdgcn_mfma_f32_16x16x32_bf16(
                    a, bfv[j], acc2[j], 0, 0, 0);
        }
        __syncthreads();   // h1s reads done -> W2s overlay allowed
        // epi: D[h][i']: reg-quad = 4 consecutive h -> packed ts[i'][h0..3]
        {
            int h0 = w * 16 + kq * 4;
#pragma unroll
            for (int j = 0; j < 5; j++) {
                int ip = j * 16 + rl;
                bf16x4 v;
#pragma unroll
                for (int r = 0; r < 4; r++)
                    v[r] = (short)f2b(acc2[j][r]);
                *(bf16x4*)&ts[ip * 264 + h0] = v;
            }
        }
        // stage W2t step0 into dbuf (over dead h1s)
        *(short8*)&W2s[rD * 40 + cD] = *(const short8*)&W2t[(size_t)rD * HH + cD];
        __syncthreads();
    }

    // ======== G3: D[i' 80][h' 256], K=256(h). wave w -> h' cols [16w,16w+16) ========
    f32x4 acc3[5];
#pragma unroll
    for (int f = 0; f < 5; f++) acc3[f] = f32x4{0.f, 0.f, 0.f, 0.f};

    for (int kk = 0; kk < 8; kk++) {
        const int cur = (kk & 1) * 10240;
        short8 w8;
        if (kk < 7)   // T14: issue early
            w8 = *(const short8*)&W2t[(size_t)rD * HH + (kk + 1) * 32 + cD];
        short8 af[5], bv;
#pragma unroll
        for (int f = 0; f < 5; f++)
            af[f] = *(const short8*)&ts[(f * 16 + rl) * 264 + kk * 32 + kq * 8];
        bv = *(const short8*)&W2s[cur + (w * 16 + rl) * 40 + kq * 8];
#pragma unroll
        for (int f = 0; f < 5; f++)
            acc3[f] = __builtin_amdgcn_mfma_f32_16x16x32_bf16(
                af[f], bv, acc3[f], 0, 0, 0);
        if (kk < 7)   // write-late into idle buffer (prev step's reads barrier'd)
            *(short8*)&W2s[(cur ^ 10240) + rD * 40 + cD] = w8;
        __syncthreads();
    }

    // ---- epi: bias+relu, in-lane pool over 20 i'-rows, slotted by kq ----
    {
        int h = w * 16 + rl;
        float bias = b2[h];
        float s = 0.f;
#pragma unroll
        for (int f = 0; f < 5; f++)
#pragma unroll
            for (int r = 0; r < 4; r++) {
                float v = acc3[f][r] + bias;
                s += v > 0.f ? v : 0.f;
            }
        pp[kq * HH + h] = s;
    }
    __syncthreads();
    // ---- head partial: out[b][s] += (sum_h ph[h]*Wo[h][s]) / NN ----
    {
        const int q = tid >> 7, s2 = tid & 127;   // 8 h-chunks of 32
        float part = 0.f;
        for (int hx = q * 32; hx < q * 32 + 32; hx++) {
            float ph = pp[0 * HH + hx] + pp[1 * HH + hx] +
                       pp[2 * HH + hx] + pp[3 * HH + hx];
            part += ph * Wo[hx * ST + s2];
        }
        pts[q * ST + s2] = part;
        __syncthreads();
        if (tid < ST) {
            float o = 0.f;
#pragma unroll
            for (int qq = 0; qq < 8; qq++) o += pts[qq * ST + tid];
            atomicAdd(&out[b * ST + tid], o * (1.0f / NN));
        }
    }
}

extern "C" void kernel_launch(void* const* d_in, const int* in_sizes, int n_in,
                              void* d_out, int out_size, void* d_ws, size_t ws_size,
                              hipStream_t stream) {
    const float* state  = (const float*)d_in[0];
    const float* action = (const float*)d_in[1];
    const int*   ei     = (const int*)d_in[2];
    const float* W1     = (const float*)d_in[3];
    const float* b1     = (const float*)d_in[4];
    const float* W2     = (const float*)d_in[5];
    const float* b2     = (const float*)d_in[6];
    const float* Wo     = (const float*)d_in[7];
    const float* bo     = (const float*)d_in[8];
    float* out = (float*)d_out;

    char* ws = (char*)d_ws;
    size_t off = 0;
    auto alloc = [&](size_t bytes) {
        void* p = ws + off;
        off += (bytes + 255) & ~(size_t)255;
        return p;
    };
    us* Pb  = (us*)alloc(NN * NN * 2);
    us* Mb  = (us*)alloc(NN * NN * 2);
    us* W1t = (us*)alloc((size_t)HH * NN * 2);
    us* W2t = (us*)alloc((size_t)HH * HH * 2);

    // 160 graph rows + 160 W1t blocks + 256 W2t blocks + 64 out-init blocks
    k_pre<<<NN + 160 + 256 + 64, 256, 0, stream>>>(ei, W1, W2, state, bo,
                                                   Pb, Mb, W1t, W2t, out);
    {
        dim3 g(2, BB);   // (i-half, batch) = 256 blocks
        k_mega<<<g, 1024, 0, stream>>>(Pb, state, action, W1t, b1, Mb, W2t, b2,
                                       Wo, out);
    }
}

// Round 17
// 35.020 us; speedup vs baseline: 3.1499x; 1.0963x over previous
//
#include <hip/hip_runtime.h>

#define NN 160      // nodes
#define BB 128      // batch
#define HH 256      // hidden
#define EE 5120     // edges
#define ST 128      // state dim
#define AC 32       // action dim
#define IH 80       // i-half rows

typedef __attribute__((ext_vector_type(8))) short short8;
typedef __attribute__((ext_vector_type(4))) short bf16x4;
typedef unsigned short us;
typedef __attribute__((ext_vector_type(4))) float f32x4;

__device__ inline us f2b(float f) {
    unsigned u = __builtin_bit_cast(unsigned, f);
    unsigned r = (u + 0x7FFFu + ((u >> 16) & 1u)) >> 16;
    return (us)r;
}
__device__ inline float b2f(us h) {
    return __builtin_bit_cast(float, (unsigned)h << 16);
}

// ---------- K1: graph rows + Pb/Mb (int-exact) + weight transposes + out init ----------
__global__ __launch_bounds__(256)
void k_pre(const int* __restrict__ ei, const float* __restrict__ W1,
           const float* __restrict__ W2, const float* __restrict__ state,
           const float* __restrict__ bo, us* __restrict__ Pb,
           us* __restrict__ Mb, us* __restrict__ W1t, us* __restrict__ W2t,
           float* __restrict__ out)
{
    const int bx = blockIdx.x, tid = threadIdx.x;
    if (bx < NN) {
        __shared__ int crow[NN];
        __shared__ unsigned abit[NN * NN / 32];   // 3.2 KB
        __shared__ float invdeg;
        if (tid < NN) crow[tid] = 0;
        for (int i = tid; i < NN * NN / 32; i += 256) abit[i] = 0;
        __syncthreads();
        for (int e = tid; e < EE; e += 256) {
            int s = ei[e], d = ei[EE + e];
            int p = d * NN + s;
            atomicOr(&abit[p >> 5], 1u << (p & 31));
            if (d == bx) atomicAdd(&crow[s], 1);
        }
        if (tid < NN) {
            int p = tid * NN + tid;
            atomicOr(&abit[p >> 5], 1u << (p & 31));
        }
        __syncthreads();
        if (tid == 0) {
            int dg = 0;
            for (int j = 0; j < NN; j++) dg += crow[j];
            invdeg = 1.0f / (float)(dg < 1 ? 1 : dg);
        }
        __syncthreads();
        if (tid < NN) {
            int s = 0;
            for (int k = 0; k < NN; k++) {
                int p = k * NN + tid;
                if (abit[p >> 5] & (1u << (p & 31))) s += crow[k];
            }
            Pb[bx * NN + tid] = f2b((float)s * invdeg);
            Mb[bx * NN + tid] = f2b((float)crow[tid] * invdeg);
        }
    } else if (bx < NN + 160) {                   // W1t: 256x160
        int idx = (bx - NN) * 256 + tid;
        int n = idx / NN, k = idx - n * NN;
        W1t[idx] = f2b(W1[k * HH + n]);
    } else if (bx < NN + 160 + 256) {             // W2t: 256x256
        int idx = (bx - NN - 160) * 256 + tid;
        int n = idx >> 8, k = idx & 255;
        W2t[idx] = f2b(W2[k * HH + n]);
    } else {                                      // out init: 128x128
        int idx = (bx - NN - 160 - 256) * 256 + tid;
        out[idx] = state[idx] + bo[idx & 127];
    }
}

// ---------- K2: 256 blocks = (i-half, batch), 1024 threads (16 waves) ----------
// G1 (full, dup x2): h1[h][k-node] = relu(sum_j Y[k][j]*W1t[h][j] + b1[h])
// G2 (i-half):       t[i'][h] = sum_k Mb[i0+i'][k]*h1[h][k]
// G3 (i-half):       acc = t @ W2t^T (W2t DIRECT from global: zero reuse per lane)
//                    -> relu+bias -> pool -> head -> atomic out
__global__ __launch_bounds__(1024, 4)
void k_mega(const us* __restrict__ Pb, const float* __restrict__ state,
            const float* __restrict__ action, const us* __restrict__ W1t,
            const float* __restrict__ b1, const us* __restrict__ Mb,
            const us* __restrict__ W2t, const float* __restrict__ b2,
            const float* __restrict__ Wo, float* __restrict__ out)
{
    __shared__ __align__(16) us h1s[256 * 168];   // 86016 B : h1
    __shared__ __align__(16) us R1[34560];        // 69120 B : {Y,W1t} -> {Mb,t,pp}
    __shared__ float xb[NN];
    us* Ys  = R1;                 // [160][40]  (12.8 KB)
    us* W1s = R1 + 6400;          // [128][168] (43 KB)
    us* Mbs = R1;                 // [80][168]  (26.9 KB)
    us* ts  = R1 + 13440;         // [80][264]  (42.2 KB)
    float* pp  = (float*)R1;          // [4][256]  (4 KB, over dead Mbs)
    float* pts = (float*)(R1 + 2048); // [8][128]  (4 KB)

    const int ihalf = blockIdx.x, b = blockIdx.y, i_base = ihalf * IH;
    const int tid = threadIdx.x, lane = tid & 63, w = tid >> 6;  // 16 waves
    const int rl = lane & 15, kq = lane >> 4;
    const int wr = w >> 3, wc = w & 7;            // G1 tiling 2(i) x 8(h)
    const int rY = tid >> 2, cY = (tid & 3) * 8;  // Y chunk (tid<640)

    if (tid < NN) xb[tid] = (tid < ST) ? state[b * ST + tid]
                                       : action[b * AC + (tid - ST)];
    __syncthreads();

    // ======== G1 (duplicated): per hh half of hidden dim ========
    for (int hh = 0; hh < 2; hh++) {
        // stage W1t half (resident) + Y step0 (streamed)
        for (int c = tid; c < 2560; c += 1024) {
            int r = c / 20, col = (c % 20) * 8;
            *(short8*)&W1s[r * 168 + col] =
                *(const short8*)&W1t[(size_t)(hh * 128 + r) * NN + col];
        }
        if (tid < 640) {
            short8 p = *(const short8*)&Pb[rY * NN + cY];
            short8 y;
#pragma unroll
            for (int u = 0; u < 8; u++)
                y[u] = (short)f2b(b2f((us)p[u]) * xb[cY + u]);
            *(short8*)&Ys[rY * 40 + cY] = y;
        }
        __syncthreads();

        f32x4 acc1[5];
#pragma unroll
        for (int f = 0; f < 5; f++) acc1[f] = f32x4{0.f, 0.f, 0.f, 0.f};

        for (int k0 = 0; k0 < NN; k0 += 32) {
            const bool nxt = (k0 + 32) < NN;
            short8 p;
            if (nxt && tid < 640)   // T14: issue early
                p = *(const short8*)&Pb[rY * NN + k0 + 32 + cY];
            short8 af[5], bv;
#pragma unroll
            for (int f = 0; f < 5; f++)
                af[f] = *(const short8*)&Ys[(wr * 80 + f * 16 + rl) * 40 + kq * 8];
            bv = *(const short8*)&W1s[(wc * 16 + rl) * 168 + k0 + kq * 8];
#pragma unroll
            for (int f = 0; f < 5; f++)
                acc1[f] = __builtin_amdgcn_mfma_f32_16x16x32_bf16(
                    af[f], bv, acc1[f], 0, 0, 0);
            __syncthreads();
            if (nxt && tid < 640) {   // write-late
                short8 y;
#pragma unroll
                for (int u = 0; u < 8; u++)
                    y[u] = (short)f2b(b2f((us)p[u]) * xb[k0 + 32 + cY + u]);
                *(short8*)&Ys[rY * 40 + cY] = y;
            }
            __syncthreads();
        }
        // epi: D[i][h]: reg-quad = 4 consecutive i -> packed h1s[h][i0..3]
        {
            int h = hh * 128 + wc * 16 + rl;
            float bias = b1[h];
#pragma unroll
            for (int f = 0; f < 5; f++) {
                int i0 = wr * 80 + f * 16 + kq * 4;
                bf16x4 v;
#pragma unroll
                for (int r = 0; r < 4; r++) {
                    float t = acc1[f][r] + bias;
                    v[r] = (short)f2b(t > 0.f ? t : 0.f);
                }
                *(bf16x4*)&h1s[h * 168 + i0] = v;
            }
        }
    }
    __syncthreads();   // G1 done: R1 free for Mbs/ts; h1s complete

    // ======== G2: D[h 256][i' 80], K=160(k). wave w -> h rows [16w,16w+16) ========
    {
        for (int c = tid; c < 1600; c += 1024) {
            int r = c / 20, col = (c % 20) * 8;
            *(short8*)&Mbs[r * 168 + col] =
                *(const short8*)&Mb[(size_t)(i_base + r) * NN + col];
        }
        __syncthreads();

        f32x4 acc2[5];
#pragma unroll
        for (int j = 0; j < 5; j++) acc2[j] = f32x4{0.f, 0.f, 0.f, 0.f};

        for (int k0 = 0; k0 < NN; k0 += 32) {    // barrier-free (both resident)
            short8 a = *(const short8*)&h1s[(w * 16 + rl) * 168 + k0 + kq * 8];
            short8 bfv[5];
#pragma unroll
            for (int j = 0; j < 5; j++)
                bfv[j] = *(const short8*)&Mbs[(j * 16 + rl) * 168 + k0 + kq * 8];
#pragma unroll
            for (int j = 0; j < 5; j++)
                acc2[j] = __builtin_amdgcn_mfma_f32_16x16x32_bf16(
                    a, bfv[j], acc2[j], 0, 0, 0);
        }
        __syncthreads();   // h1s/Mbs reads done
        // epi: D[h][i']: reg-quad = 4 consecutive h -> packed ts[i'][h0..3]
        {
            int h0 = w * 16 + kq * 4;
#pragma unroll
            for (int j = 0; j < 5; j++) {
                int ip = j * 16 + rl;
                bf16x4 v;
#pragma unroll
                for (int r = 0; r < 4; r++)
                    v[r] = (short)f2b(acc2[j][r]);
                *(bf16x4*)&ts[ip * 264 + h0] = v;
            }
        }
        __syncthreads();   // ts complete for cross-wave G3 reads
    }

    // ======== G3: D[i' 80][h' 256], K=256(h). BARRIER-FREE ========
    // wave w -> h' rows [16w,16w+16); each W2t 16B fragment consumed by
    // exactly one lane => direct global load (L2-hot), no LDS round-trip.
    f32x4 acc3[5];
#pragma unroll
    for (int f = 0; f < 5; f++) acc3[f] = f32x4{0.f, 0.f, 0.f, 0.f};

    {
        const us* w2row = W2t + (size_t)(w * 16 + rl) * HH + kq * 8;
#pragma unroll
        for (int kk = 0; kk < 8; kk++) {
            short8 bv = *(const short8*)&w2row[kk * 32];
            short8 af[5];
#pragma unroll
            for (int f = 0; f < 5; f++)
                af[f] = *(const short8*)&ts[(f * 16 + rl) * 264 + kk * 32 + kq * 8];
#pragma unroll
            for (int f = 0; f < 5; f++)
                acc3[f] = __builtin_amdgcn_mfma_f32_16x16x32_bf16(
                    af[f], bv, acc3[f], 0, 0, 0);
        }
    }
    __syncthreads();   // ts reads done; R1 front region reusable for pp/pts

    // ---- epi: bias+relu, in-lane pool over 20 i'-rows, slotted by kq ----
    {
        int h = w * 16 + rl;
        float bias = b2[h];
        float s = 0.f;
#pragma unroll
        for (int f = 0; f < 5; f++)
#pragma unroll
            for (int r = 0; r < 4; r++) {
                float v = acc3[f][r] + bias;
                s += v > 0.f ? v : 0.f;
            }
        pp[kq * HH + h] = s;
    }
    __syncthreads();
    // ---- head partial: out[b][s] += (sum_h ph[h]*Wo[h][s]) / NN ----
    {
        const int q = tid >> 7, s2 = tid & 127;   // 8 h-chunks of 32
        float part = 0.f;
        for (int hx = q * 32; hx < q * 32 + 32; hx++) {
            float ph = pp[0 * HH + hx] + pp[1 * HH + hx] +
                       pp[2 * HH + hx] + pp[3 * HH + hx];
            part += ph * Wo[hx * ST + s2];
        }
        pts[q * ST + s2] = part;
        __syncthreads();
        if (tid < ST) {
            float o = 0.f;
#pragma unroll
            for (int qq = 0; qq < 8; qq++) o += pts[qq * ST + tid];
            atomicAdd(&out[b * ST + tid], o * (1.0f / NN));
        }
    }
}

extern "C" void kernel_launch(void* const* d_in, const int* in_sizes, int n_in,
                              void* d_out, int out_size, void* d_ws, size_t ws_size,
                              hipStream_t stream) {
    const float* state  = (const float*)d_in[0];
    const float* action = (const float*)d_in[1];
    const int*   ei     = (const int*)d_in[2];
    const float* W1     = (const float*)d_in[3];
    const float* b1     = (const float*)d_in[4];
    const float* W2     = (const float*)d_in[5];
    const float* b2     = (const float*)d_in[6];
    const float* Wo     = (const float*)d_in[7];
    const float* bo     = (const float*)d_in[8];
    float* out = (float*)d_out;

    char* ws = (char*)d_ws;
    size_t off = 0;
    auto alloc = [&](size_t bytes) {
        void* p = ws + off;
        off += (bytes + 255) & ~(size_t)255;
        return p;
    };
    us* Pb  = (us*)alloc(NN * NN * 2);
    us* Mb  = (us*)alloc(NN * NN * 2);
    us* W1t = (us*)alloc((size_t)HH * NN * 2);
    us* W2t = (us*)alloc((size_t)HH * HH * 2);

    // 160 graph rows + 160 W1t blocks + 256 W2t blocks + 64 out-init blocks
    k_pre<<<NN + 160 + 256 + 64, 256, 0, stream>>>(ei, W1, W2, state, bo,
                                                   Pb, Mb, W1t, W2t, out);
    {
        dim3 g(2, BB);   // (i-half, batch) = 256 blocks
        k_mega<<<g, 1024, 0, stream>>>(Pb, state, action, W1t, b1, Mb, W2t, b2,
                                       Wo, out);
    }
}

// Round 18
// 33.131 us; speedup vs baseline: 3.3295x; 1.0570x over previous
//
#include <hip/hip_runtime.h>

#define NN 160      // nodes
#define BB 128      // batch
#define HH 256      // hidden
#define EE 5120     // edges
#define ST 128      // state dim
#define AC 32       // action dim
#define IH 80       // i-half rows

typedef __attribute__((ext_vector_type(8))) short short8;
typedef __attribute__((ext_vector_type(4))) short bf16x4;
typedef unsigned short us;
typedef __attribute__((ext_vector_type(4))) float f32x4;

__device__ inline us f2b(float f) {
    unsigned u = __builtin_bit_cast(unsigned, f);
    unsigned r = (u + 0x7FFFu + ((u >> 16) & 1u)) >> 16;
    return (us)r;
}
__device__ inline float b2f(us h) {
    return __builtin_bit_cast(float, (unsigned)h << 16);
}

// ---------- K1: graph rows + Pb/Mb (int-exact) + weight transposes + out init ----------
__global__ __launch_bounds__(256)
void k_pre(const int* __restrict__ ei, const float* __restrict__ W1,
           const float* __restrict__ W2, const float* __restrict__ state,
           const float* __restrict__ bo, us* __restrict__ Pb,
           us* __restrict__ Mb, us* __restrict__ W1t, us* __restrict__ W2t,
           float* __restrict__ out)
{
    const int bx = blockIdx.x, tid = threadIdx.x;
    if (bx < NN) {
        __shared__ int crow[NN];
        __shared__ unsigned abit[NN * NN / 32];   // 3.2 KB
        __shared__ float invdeg;
        if (tid < NN) crow[tid] = 0;
        for (int i = tid; i < NN * NN / 32; i += 256) abit[i] = 0;
        __syncthreads();
        for (int e = tid; e < EE; e += 256) {
            int s = ei[e], d = ei[EE + e];
            int p = d * NN + s;
            atomicOr(&abit[p >> 5], 1u << (p & 31));
            if (d == bx) atomicAdd(&crow[s], 1);
        }
        if (tid < NN) {
            int p = tid * NN + tid;
            atomicOr(&abit[p >> 5], 1u << (p & 31));
        }
        __syncthreads();
        if (tid == 0) {
            int dg = 0;
            for (int j = 0; j < NN; j++) dg += crow[j];
            invdeg = 1.0f / (float)(dg < 1 ? 1 : dg);
        }
        __syncthreads();
        if (tid < NN) {
            int s = 0;
            for (int k = 0; k < NN; k++) {
                int p = k * NN + tid;
                if (abit[p >> 5] & (1u << (p & 31))) s += crow[k];
            }
            Pb[bx * NN + tid] = f2b((float)s * invdeg);
            Mb[bx * NN + tid] = f2b((float)crow[tid] * invdeg);
        }
    } else if (bx < NN + 160) {                   // W1t: 256x160
        int idx = (bx - NN) * 256 + tid;
        int n = idx / NN, k = idx - n * NN;
        W1t[idx] = f2b(W1[k * HH + n]);
    } else if (bx < NN + 160 + 256) {             // W2t: 256x256
        int idx = (bx - NN - 160) * 256 + tid;
        int n = idx >> 8, k = idx & 255;
        W2t[idx] = f2b(W2[k * HH + n]);
    } else {                                      // out init: 128x128
        int idx = (bx - NN - 160 - 256) * 256 + tid;
        out[idx] = state[idx] + bo[idx & 127];
    }
}

// ---------- K2: 256 blocks = (i-half, batch), 1024 threads (16 waves) ----------
// Ys resident [160][168] (staged+computed ONCE); W1t/Mb/W2t direct from global
// (reuse 2x/16x/1x -> L2);  6 barriers total.
// G1 (dup x2, barrier-free): h1[h][k] = relu(sum_j Y[k][j]*W1t[h][j] + b1[h])
// G2 (barrier-free):         t[i'][h] = sum_k Mb[i0+i'][k]*h1[h][k]
// G3 (barrier-free):         acc = t @ W2t^T -> relu+bias -> pool -> head -> out
__global__ __launch_bounds__(1024, 4)
void k_mega(const us* __restrict__ Pb, const float* __restrict__ state,
            const float* __restrict__ action, const us* __restrict__ W1t,
            const float* __restrict__ b1, const us* __restrict__ Mb,
            const us* __restrict__ W2t, const float* __restrict__ b2,
            const float* __restrict__ Wo, float* __restrict__ out)
{
    // LDS (shorts): Ys [160][168] = 26880 (after G1: ts[80][264]=21120 overlays;
    //               tail 21120.. = pp[4][256] + pts[8][128] f32)
    //               h1s [256][168] = 43008    => 69888 sh = 139776 B
    __shared__ __align__(16) us SH[69888];
    __shared__ float xb[NN];
    us* Ys  = SH;                     // [160][168]
    us* ts  = SH;                     // [80][264] overlays Ys after G1
    us* h1s = SH + 26880;             // [256][168]
    float* pp  = (float*)&SH[21120];  // [4][256] f32 (Ys tail, disjoint from ts)
    float* pts = (float*)&SH[23168];  // [8][128] f32

    const int ihalf = blockIdx.x, b = blockIdx.y, i_base = ihalf * IH;
    const int tid = threadIdx.x, lane = tid & 63, w = tid >> 6;  // 16 waves
    const int rl = lane & 15, kq = lane >> 4;
    const int wr = w >> 3, wc = w & 7;            // G1 tiling 2(i) x 8(h)

    if (tid < NN) xb[tid] = (tid < ST) ? state[b * ST + tid]
                                       : action[b * AC + (tid - ST)];
    __syncthreads();                                           // B1: xb ready

    // ---- stage Y = bf16(Pb*x) ONCE, fully resident ----
    for (int c = tid; c < 3200; c += 1024) {
        int r = c / 20, col = (c % 20) * 8;
        short8 p = *(const short8*)&Pb[r * NN + col];
        short8 y;
#pragma unroll
        for (int u = 0; u < 8; u++)
            y[u] = (short)f2b(b2f((us)p[u]) * xb[col + u]);
        *(short8*)&Ys[r * 168 + col] = y;
    }
    __syncthreads();                                           // B2: Ys resident

    // ======== G1 (dup x2), BARRIER-FREE: A=Ys (LDS, 8x reuse), B=W1t (global, 2x) ========
    for (int hh = 0; hh < 2; hh++) {
        f32x4 acc1[5];
#pragma unroll
        for (int f = 0; f < 5; f++) acc1[f] = f32x4{0.f, 0.f, 0.f, 0.f};

        const us* w1row = W1t + (size_t)(hh * 128 + wc * 16 + rl) * NN + kq * 8;
#pragma unroll
        for (int kk = 0; kk < 5; kk++) {
            short8 bv = *(const short8*)&w1row[kk * 32];
            short8 af[5];
#pragma unroll
            for (int f = 0; f < 5; f++)
                af[f] = *(const short8*)&Ys[(wr * 80 + f * 16 + rl) * 168 + kk * 32 + kq * 8];
#pragma unroll
            for (int f = 0; f < 5; f++)
                acc1[f] = __builtin_amdgcn_mfma_f32_16x16x32_bf16(
                    af[f], bv, acc1[f], 0, 0, 0);
        }
        // epi: D[i][h]: 4 consecutive i per reg-quad -> packed h1s[h][i0..3]
        {
            int h = hh * 128 + wc * 16 + rl;
            float bias = b1[h];
#pragma unroll
            for (int f = 0; f < 5; f++) {
                int i0 = wr * 80 + f * 16 + kq * 4;
                bf16x4 v;
#pragma unroll
                for (int r = 0; r < 4; r++) {
                    float t = acc1[f][r] + bias;
                    v[r] = (short)f2b(t > 0.f ? t : 0.f);
                }
                *(bf16x4*)&h1s[h * 168 + i0] = v;
            }
        }
    }
    __syncthreads();                        // B3: h1s complete; Ys dead

    // ======== G2, BARRIER-FREE: A=h1s (LDS, own row), B=Mb (global, L2) ========
    // D[h 256][i' 80]; wave w -> h rows [16w,16w+16)
    {
        f32x4 acc2[5];
#pragma unroll
        for (int j = 0; j < 5; j++) acc2[j] = f32x4{0.f, 0.f, 0.f, 0.f};

#pragma unroll
        for (int kk = 0; kk < 5; kk++) {
            short8 a = *(const short8*)&h1s[(w * 16 + rl) * 168 + kk * 32 + kq * 8];
            short8 bfv[5];
#pragma unroll
            for (int j = 0; j < 5; j++)
                bfv[j] = *(const short8*)&Mb[(size_t)(i_base + j * 16 + rl) * NN + kk * 32 + kq * 8];
#pragma unroll
            for (int j = 0; j < 5; j++)
                acc2[j] = __builtin_amdgcn_mfma_f32_16x16x32_bf16(
                    a, bfv[j], acc2[j], 0, 0, 0);
        }
        // epi: D[h][i']: 4 consecutive h per reg-quad -> packed ts[i'][h0..3]
        {
            int h0 = w * 16 + kq * 4;
#pragma unroll
            for (int j = 0; j < 5; j++) {
                int ip = j * 16 + rl;
                bf16x4 v;
#pragma unroll
                for (int r = 0; r < 4; r++)
                    v[r] = (short)f2b(acc2[j][r]);
                *(bf16x4*)&ts[ip * 264 + h0] = v;
            }
        }
    }
    __syncthreads();                        // B4: ts complete

    // ======== G3, BARRIER-FREE: A=ts (LDS), B=W2t (global direct, 1x reuse) ========
    f32x4 acc3[5];
#pragma unroll
    for (int f = 0; f < 5; f++) acc3[f] = f32x4{0.f, 0.f, 0.f, 0.f};
    {
        const us* w2row = W2t + (size_t)(w * 16 + rl) * HH + kq * 8;
#pragma unroll
        for (int kk = 0; kk < 8; kk++) {
            short8 bv = *(const short8*)&w2row[kk * 32];
            short8 af[5];
#pragma unroll
            for (int f = 0; f < 5; f++)
                af[f] = *(const short8*)&ts[(f * 16 + rl) * 264 + kk * 32 + kq * 8];
#pragma unroll
            for (int f = 0; f < 5; f++)
                acc3[f] = __builtin_amdgcn_mfma_f32_16x16x32_bf16(
                    af[f], bv, acc3[f], 0, 0, 0);
        }
    }

    // ---- epi: bias+relu, in-lane pool over 20 i'-rows, slotted by kq ----
    // pp region (Ys tail) is disjoint from ts -> no barrier needed before write
    {
        int h = w * 16 + rl;
        float bias = b2[h];
        float s = 0.f;
#pragma unroll
        for (int f = 0; f < 5; f++)
#pragma unroll
            for (int r = 0; r < 4; r++) {
                float v = acc3[f][r] + bias;
                s += v > 0.f ? v : 0.f;
            }
        pp[kq * HH + h] = s;
    }
    __syncthreads();                        // B5: pp complete
    // ---- head partial: out[b][s] += (sum_h ph[h]*Wo[h][s]) / NN ----
    {
        const int q = tid >> 7, s2 = tid & 127;   // 8 h-chunks of 32
        float part = 0.f;
        for (int hx = q * 32; hx < q * 32 + 32; hx++) {
            float ph = pp[0 * HH + hx] + pp[1 * HH + hx] +
                       pp[2 * HH + hx] + pp[3 * HH + hx];
            part += ph * Wo[hx * ST + s2];
        }
        pts[q * ST + s2] = part;
        __syncthreads();                    // B6: pts complete
        if (tid < ST) {
            float o = 0.f;
#pragma unroll
            for (int qq = 0; qq < 8; qq++) o += pts[qq * ST + tid];
            atomicAdd(&out[b * ST + tid], o * (1.0f / NN));
        }
    }
}

extern "C" void kernel_launch(void* const* d_in, const int* in_sizes, int n_in,
                              void* d_out, int out_size, void* d_ws, size_t ws_size,
                              hipStream_t stream) {
    const float* state  = (const float*)d_in[0];
    const float* action = (const float*)d_in[1];
    const int*   ei     = (const int*)d_in[2];
    const float* W1     = (const float*)d_in[3];
    const float* b1     = (const float*)d_in[4];
    const float* W2     = (const float*)d_in[5];
    const float* b2     = (const float*)d_in[6];
    const float* Wo     = (const float*)d_in[7];
    const float* bo     = (const float*)d_in[8];
    float* out = (float*)d_out;

    char* ws = (char*)d_ws;
    size_t off = 0;
    auto alloc = [&](size_t bytes) {
        void* p = ws + off;
        off += (bytes + 255) & ~(size_t)255;
        return p;
    };
    us* Pb  = (us*)alloc(NN * NN * 2);
    us* Mb  = (us*)alloc(NN * NN * 2);
    us* W1t = (us*)alloc((size_t)HH * NN * 2);
    us* W2t = (us*)alloc((size_t)HH * HH * 2);

    // 160 graph rows + 160 W1t blocks + 256 W2t blocks + 64 out-init blocks
    k_pre<<<NN + 160 + 256 + 64, 256, 0, stream>>>(ei, W1, W2, state, bo,
                                                   Pb, Mb, W1t, W2t, out);
    {
        dim3 g(2, BB);   // (i-half, batch) = 256 blocks
        k_mega<<<g, 1024, 0, stream>>>(Pb, state, action, W1t, b1, Mb, W2t, b2,
                                       Wo, out);
    }
}

// Round 20
// 31.046 us; speedup vs baseline: 3.5531x; 1.0672x over previous
//
#include <hip/hip_runtime.h>

#define NN 160      // nodes
#define BB 128      // batch
#define HH 256      // hidden
#define EE 5120     // edges
#define ST 128      // state dim
#define AC 32       // action dim
#define IH 80       // i-half rows

typedef __attribute__((ext_vector_type(8))) short short8;
typedef __attribute__((ext_vector_type(4))) short bf16x4;
typedef unsigned short us;
typedef __attribute__((ext_vector_type(4))) float f32x4;

__device__ inline us f2b(float f) {
    unsigned u = __builtin_bit_cast(unsigned, f);
    unsigned r = (u + 0x7FFFu + ((u >> 16) & 1u)) >> 16;
    return (us)r;
}
__device__ inline float b2f(us h) {
    return __builtin_bit_cast(float, (unsigned)h << 16);
}

// ---------- K1: graph rows + Pb/Mb (int-exact) + weight transposes + out init ----------
__global__ __launch_bounds__(256)
void k_pre(const int* __restrict__ ei, const float* __restrict__ W1,
           const float* __restrict__ W2, const float* __restrict__ state,
           const float* __restrict__ bo, us* __restrict__ Pb,
           us* __restrict__ Mb, us* __restrict__ W1t, us* __restrict__ W2t,
           float* __restrict__ out)
{
    const int bx = blockIdx.x, tid = threadIdx.x;
    if (bx < NN) {
        __shared__ int crow[NN];
        __shared__ unsigned abit[NN * NN / 32];   // 3.2 KB
        __shared__ float invdeg;
        if (tid < NN) crow[tid] = 0;
        for (int i = tid; i < NN * NN / 32; i += 256) abit[i] = 0;
        __syncthreads();
        for (int e = tid; e < EE; e += 256) {
            int s = ei[e], d = ei[EE + e];
            int p = d * NN + s;
            atomicOr(&abit[p >> 5], 1u << (p & 31));
            if (d == bx) atomicAdd(&crow[s], 1);
        }
        if (tid < NN) {
            int p = tid * NN + tid;
            atomicOr(&abit[p >> 5], 1u << (p & 31));
        }
        __syncthreads();
        if (tid == 0) {
            int dg = 0;
            for (int j = 0; j < NN; j++) dg += crow[j];
            invdeg = 1.0f / (float)(dg < 1 ? 1 : dg);
        }
        __syncthreads();
        if (tid < NN) {
            int s = 0;
            for (int k = 0; k < NN; k++) {
                int p = k * NN + tid;
                if (abit[p >> 5] & (1u << (p & 31))) s += crow[k];
            }
            Pb[bx * NN + tid] = f2b((float)s * invdeg);
            Mb[bx * NN + tid] = f2b((float)crow[tid] * invdeg);
        }
    } else if (bx < NN + 160) {                   // W1t: 256x160
        int idx = (bx - NN) * 256 + tid;
        int n = idx / NN, k = idx - n * NN;
        W1t[idx] = f2b(W1[k * HH + n]);
    } else if (bx < NN + 160 + 256) {             // W2t: 256x256
        int idx = (bx - NN - 160) * 256 + tid;
        int n = idx >> 8, k = idx & 255;
        W2t[idx] = f2b(W2[k * HH + n]);
    } else {                                      // out init: 128x128
        int idx = (bx - NN - 160 - 256) * 256 + tid;
        out[idx] = state[idx] + bo[idx & 127];
    }
}

// ---------- K2: 256 blocks = (i-half, batch), 1024 threads (16 waves) ----------
// Reuse-matched placement: Ys (8x) + Mbs (16x) in LDS; W1t/W2t (1x) direct global.
// G1 single-pass (wave w owns h=16w+rl, all 256 h; W1t fragments read ONCE).
// ts[80][264] overlays DEAD h1s (barrier-separated). ~10 barriers total.
__global__ __launch_bounds__(1024, 4)
void k_mega(const us* __restrict__ Pb, const float* __restrict__ state,
            const float* __restrict__ action, const us* __restrict__ W1t,
            const float* __restrict__ b1, const us* __restrict__ Mb,
            const us* __restrict__ W2t, const float* __restrict__ b2,
            const float* __restrict__ Wo, float* __restrict__ out)
{
    // SH regions (shorts):
    //  Ys  @0      [160][168] = 26880   (G1 input; dead after B3)
    //    recycled: Mbs @0 [80][168]=13440 ; pp f32 @13440 (2048 sh) ;
    //              pts f32 @15488 (1024 sh)  -- all within 26880
    //  h1s @26880  [256][168] = 43008   (G1 out, G2 in; dead after B5)
    //    recycled: ts @26880 [80][264] = 21120 (extent 21112, fits)
    __shared__ __align__(16) us SH[69888];        // 139776 B
    __shared__ float xb[NN];
    us* Ys  = SH;
    us* h1s = SH + 26880;
    us* Mbs = SH;
    us* ts  = SH + 26880;
    float* pp  = (float*)&SH[13440];  // [4][256] f32
    float* pts = (float*)&SH[15488];  // [4][128] f32

    const int ihalf = blockIdx.x, b = blockIdx.y, i_base = ihalf * IH;
    const int tid = threadIdx.x, lane = tid & 63, w = tid >> 6;  // 16 waves
    const int rl = lane & 15, kq = lane >> 4;

    if (tid < NN) xb[tid] = (tid < ST) ? state[b * ST + tid]
                                       : action[b * AC + (tid - ST)];
    __syncthreads();                                           // B1: xb

    // ---- stage Y = bf16(Pb*x) once, resident ----
    for (int c = tid; c < 3200; c += 1024) {
        int r = c / 20, col = (c % 20) * 8;
        short8 p = *(const short8*)&Pb[r * NN + col];
        short8 y;
#pragma unroll
        for (int u = 0; u < 8; u++)
            y[u] = (short)f2b(b2f((us)p[u]) * xb[col + u]);
        *(short8*)&Ys[r * 168 + col] = y;
    }
    __syncthreads();                                           // B2: Ys

    // ======== G1 single pass, barrier-free ========
    // wave w: h = 16w+rl (all 256 h in one pass); A = Ys (10 i-frags)
    {
        f32x4 acc1[10];
#pragma unroll
        for (int f = 0; f < 10; f++) acc1[f] = f32x4{0.f, 0.f, 0.f, 0.f};

        const us* w1row = W1t + (size_t)(w * 16 + rl) * NN + kq * 8;
#pragma unroll
        for (int kk = 0; kk < 5; kk++) {
            short8 bv = *(const short8*)&w1row[kk * 32];
            short8 af[10];
#pragma unroll
            for (int f = 0; f < 10; f++)
                af[f] = *(const short8*)&Ys[(f * 16 + rl) * 168 + kk * 32 + kq * 8];
#pragma unroll
            for (int f = 0; f < 10; f++)
                acc1[f] = __builtin_amdgcn_mfma_f32_16x16x32_bf16(
                    af[f], bv, acc1[f], 0, 0, 0);
        }
        // epi: D[i][h]: col h = 16w+rl, rows i = f*16 + kq*4 + r
        int h = w * 16 + rl;
        float bias = b1[h];
#pragma unroll
        for (int f = 0; f < 10; f++) {
            int i0 = f * 16 + kq * 4;
            bf16x4 v;
#pragma unroll
            for (int r = 0; r < 4; r++) {
                float t = acc1[f][r] + bias;
                v[r] = (short)f2b(t > 0.f ? t : 0.f);
            }
            *(bf16x4*)&h1s[h * 168 + i0] = v;
        }
    }
    __syncthreads();                        // B3: h1s complete; Ys dead

    // ---- stage Mbs (16x reuse) into dead Ys region ----
    for (int c = tid; c < 1600; c += 1024) {
        int r = c / 20, col = (c % 20) * 8;
        *(short8*)&Mbs[r * 168 + col] =
            *(const short8*)&Mb[(size_t)(i_base + r) * NN + col];
    }
    __syncthreads();                        // B4: Mbs ready

    // ======== G2 MFMAs, barrier-free (h1s + Mbs resident; acc in regs) ========
    f32x4 acc2[5];
#pragma unroll
    for (int j = 0; j < 5; j++) acc2[j] = f32x4{0.f, 0.f, 0.f, 0.f};
#pragma unroll
    for (int kk = 0; kk < 5; kk++) {
        short8 a = *(const short8*)&h1s[(w * 16 + rl) * 168 + kk * 32 + kq * 8];
        short8 bfv[5];
#pragma unroll
        for (int j = 0; j < 5; j++)
            bfv[j] = *(const short8*)&Mbs[(j * 16 + rl) * 168 + kk * 32 + kq * 8];
#pragma unroll
        for (int j = 0; j < 5; j++)
            acc2[j] = __builtin_amdgcn_mfma_f32_16x16x32_bf16(
                a, bfv[j], acc2[j], 0, 0, 0);
    }
    __syncthreads();                        // B5: all h1s reads done -> ts overlay safe

    // ---- G2 epi: D[h][i']: 4 consec h per reg-quad -> packed ts[i'][h0..3] ----
    {
        int h0 = w * 16 + kq * 4;
#pragma unroll
        for (int j = 0; j < 5; j++) {
            int ip = j * 16 + rl;
            bf16x4 v;
#pragma unroll
            for (int r = 0; r < 4; r++)
                v[r] = (short)f2b(acc2[j][r]);
            *(bf16x4*)&ts[ip * 264 + h0] = v;
        }
    }
    __syncthreads();                        // B6: ts ready

    // ======== G3, barrier-free: A=ts (LDS), B=W2t (global, 1x) ========
    f32x4 acc3[5];
#pragma unroll
    for (int f = 0; f < 5; f++) acc3[f] = f32x4{0.f, 0.f, 0.f, 0.f};
    {
        const us* w2row = W2t + (size_t)(w * 16 + rl) * HH + kq * 8;
#pragma unroll
        for (int kk = 0; kk < 8; kk++) {
            short8 bv = *(const short8*)&w2row[kk * 32];
            short8 af[5];
#pragma unroll
            for (int f = 0; f < 5; f++)
                af[f] = *(const short8*)&ts[(f * 16 + rl) * 264 + kk * 32 + kq * 8];
#pragma unroll
            for (int f = 0; f < 5; f++)
                acc3[f] = __builtin_amdgcn_mfma_f32_16x16x32_bf16(
                    af[f], bv, acc3[f], 0, 0, 0);
        }
    }

    // ---- epi: bias+relu, in-lane pool over 20 i'-rows, slot by kq ----
    // pp (Ys region @13440) is disjoint from ts (h1s region) -> safe pre-barrier
    {
        int h = w * 16 + rl;
        float bias = b2[h];
        float s = 0.f;
#pragma unroll
        for (int f = 0; f < 5; f++)
#pragma unroll
            for (int r = 0; r < 4; r++) {
                float v = acc3[f][r] + bias;
                s += v > 0.f ? v : 0.f;
            }
        pp[kq * HH + h] = s;
    }
    __syncthreads();                        // B7: pp done
    // ---- head partial: out[b][s] += (sum_h ph[h]*Wo[h][s]) / NN ----
    {
        const int q8 = tid >> 7, s128 = tid & 127;   // 8 h-chunks of 32
        float part = 0.f;
        for (int hx = q8 * 32; hx < q8 * 32 + 32; hx++) {
            float ph = pp[0 * HH + hx] + pp[1 * HH + hx] +
                       pp[2 * HH + hx] + pp[3 * HH + hx];
            part += ph * Wo[hx * ST + s128];
        }
        if (q8 < 4) pts[q8 * ST + s128] = part;
        __syncthreads();                    // B8
        if (q8 >= 4) atomicAdd(&pts[(q8 - 4) * ST + s128], part);
        __syncthreads();                    // B9: pts done
        if (tid < ST) {
            float o = pts[0 * ST + tid] + pts[1 * ST + tid] +
                      pts[2 * ST + tid] + pts[3 * ST + tid];
            atomicAdd(&out[b * ST + tid], o * (1.0f / NN));
        }
    }
}

extern "C" void kernel_launch(void* const* d_in, const int* in_sizes, int n_in,
                              void* d_out, int out_size, void* d_ws, size_t ws_size,
                              hipStream_t stream) {
    const float* state  = (const float*)d_in[0];
    const float* action = (const float*)d_in[1];
    const int*   ei     = (const int*)d_in[2];
    const float* W1     = (const float*)d_in[3];
    const float* b1     = (const float*)d_in[4];
    const float* W2     = (const float*)d_in[5];
    const float* b2     = (const float*)d_in[6];
    const float* Wo     = (const float*)d_in[7];
    const float* bo     = (const float*)d_in[8];
    float* out = (float*)d_out;

    char* ws = (char*)d_ws;
    size_t off = 0;
    auto alloc = [&](size_t bytes) {
        void* p = ws + off;
        off += (bytes + 255) & ~(size_t)255;
        return p;
    };
    us* Pb  = (us*)alloc(NN * NN * 2);
    us* Mb  = (us*)alloc(NN * NN * 2);
    us* W1t = (us*)alloc((size_t)HH * NN * 2);
    us* W2t = (us*)alloc((size_t)HH * HH * 2);

    // 160 graph rows + 160 W1t blocks + 256 W2t blocks + 64 out-init blocks
    k_pre<<<NN + 160 + 256 + 64, 256, 0, stream>>>(ei, W1, W2, state, bo,
                                                   Pb, Mb, W1t, W2t, out);
    {
        dim3 g(2, BB);   // (i-half, batch) = 256 blocks
        k_mega<<<g, 1024, 0, stream>>>(Pb, state, action, W1t, b1, Mb, W2t, b2,
                                       Wo, out);
    }
}